// Round 5
// baseline (164.719 us; speedup 1.0000x reference)
//
#include <hip/hip_runtime.h>
#include <math.h>

#define N_EXC   20000
#define N_KCC   1024
#define FDIM    128
#define LEAKY_S 0.2f

#define BR  32       // exercise rows per block
#define TJ  64       // kc (j) tile (16 tiles), double-buffered
#define EXS 136      // ex staging stride in ushorts (272 B)
#define WST 72       // w tile stride in ushorts (144 B)

typedef unsigned short ushort_t;
typedef __attribute__((ext_vector_type(8))) short short8;
typedef __attribute__((ext_vector_type(4))) float floatx4;

__device__ __forceinline__ ushort_t f2bf(float f) {
    unsigned u = __float_as_uint(f);
    u += 0x7FFF + ((u >> 16) & 1);          // RNE
    return (ushort_t)(u >> 16);
}

// async global->LDS, 16 B per lane. LDS dest must be wave-uniform base + lane*16.
__device__ __forceinline__ void async16(const void* g, void* l) {
    __builtin_amdgcn_global_load_lds(
        (const __attribute__((address_space(1))) unsigned int*)g,
        (__attribute__((address_space(3))) unsigned int*)l,
        16, 0, 0);
}

// ws layout (float offsets):
//   [0)     tarr  1024 f32
//   [1024)  w1a1  128 f32
//   [1152)  kc_sw 131072 ushorts (256 KB): 16 tiles x [f=128][c'=8][e=8],
//           tile jt = j>>6, chunk c = (j&63)>>3, c' = c ^ (f&7), val = bf16(kcWh[j][f])
//   [+256K) E_sw  16384 ushorts (32 KB): 2 halves (k<64, k>=64) x [n=128][c'=8][e=8],
//           c' = ((k&63)>>3) ^ (n&7), val = bf16(E[k][n])

__global__ __launch_bounds__(256) void gat_prep(const float* __restrict__ kc_h,
                                                const float* __restrict__ W1,
                                                const float* __restrict__ E,
                                                const float* __restrict__ a,
                                                float* __restrict__ ws)
{
    float* tarr = ws;
    float* w1a1 = ws + N_KCC;
    ushort_t* kc_sw = (ushort_t*)(ws + N_KCC + FDIM);
    ushort_t* E_sw  = kc_sw + FDIM * N_KCC;
    const int tid = threadIdx.x;
    const int b = blockIdx.x;

    __shared__ __align__(16) float kct[128 * 132];     // 67.6 KB
    __shared__ __align__(16) ushort_t sw[32 * 128];    // 8 KB
    __shared__ __align__(16) float w1a2_lds[FDIM];

    if (b < 32) {
        // kcWh: j-block jb (128 rows = tiles jb*2, jb*2+1), f-quarter fq (32 cols)
        const int jb = b >> 2, fq = b & 3;
        const float* kcbase = kc_h + (size_t)jb * 128 * FDIM;
        #pragma unroll
        for (int u = 0; u < 16; ++u) {
            int flat = u * 256 + tid;
            int r = flat >> 5, c4 = (flat & 31) * 4;
            float4 v = *(const float4*)(kcbase + r * FDIM + c4);
            kct[r * 132 + c4 + 0] = v.x; kct[r * 132 + c4 + 1] = v.y;
            kct[r * 132 + c4 + 2] = v.z; kct[r * 132 + c4 + 3] = v.w;
        }
        __syncthreads();
        const int jg = tid >> 4;                 // j rows jg*8..+7 (within 128-block)
        const int fg = tid & 15;                 // 2 f cols
        const int f0 = fq * 32 + fg * 2;
        float acc[8][2];
        #pragma unroll
        for (int i = 0; i < 8; ++i) { acc[i][0] = 0.f; acc[i][1] = 0.f; }
        for (int k4 = 0; k4 < FDIM; k4 += 4) {
            float4 av[8];
            #pragma unroll
            for (int i = 0; i < 8; ++i)
                av[i] = *(const float4*)(kct + (jg * 8 + i) * 132 + k4);
            #pragma unroll
            for (int kk = 0; kk < 4; ++kk) {
                float2 bv = *(const float2*)(W1 + (k4 + kk) * FDIM + f0);
                #pragma unroll
                for (int i = 0; i < 8; ++i) {
                    float a_ = ((const float*)&av[i])[kk];
                    acc[i][0] += a_ * bv.x;
                    acc[i][1] += a_ * bv.y;
                }
            }
        }
        // pack 8 j per (f) into uint4; tile-local chunk: jtl = jg>>3, c' = (jg&7)^(f&7)
        #pragma unroll
        for (int c = 0; c < 2; ++c) {
            int f = f0 + c;
            int fl = fg * 2 + c;
            unsigned pk[4];
            #pragma unroll
            for (int i = 0; i < 4; ++i)
                pk[i] = (unsigned)f2bf(acc[2 * i][c]) | ((unsigned)f2bf(acc[2 * i + 1][c]) << 16);
            int jtl = jg >> 3;
            int cpp = (jg & 7) ^ (f & 7);
            *(uint4*)(sw + fl * 128 + jtl * 64 + cpp * 8) = make_uint4(pk[0], pk[1], pk[2], pk[3]);
        }
        __syncthreads();
        // copy out: chunk flat = fl*16 + jtl*8 + c'  (sw is exactly flat*8)
        #pragma unroll
        for (int u = 0; u < 2; ++u) {
            int flat = u * 256 + tid;            // 0..511 chunks
            int fl = flat >> 4;
            int rem = flat & 15;
            int jtl = rem >> 3, cpp = rem & 7;
            ushort_t* dst = kc_sw + ((size_t)(jb * 2 + jtl)) * 8192
                          + (fq * 32 + fl) * 64 + cpp * 8;
            *(uint4*)dst = *(const uint4*)(sw + flat * 8);
        }
        return;
    }

    if (b < 36) {
        // t[j] = kc[j] . (W1 @ a2); block 32 also writes w1a1
        if (tid >= 128) {
            int k = tid - 128;
            float acc = 0.f;
            const float* row = W1 + k * FDIM;
            #pragma unroll 8
            for (int f = 0; f < FDIM; ++f) acc += row[f] * a[FDIM + f];
            w1a2_lds[k] = acc;
        } else if (b == 32) {
            float acc = 0.f;
            const float* row = W1 + tid * FDIM;
            #pragma unroll 8
            for (int f = 0; f < FDIM; ++f) acc += row[f] * a[f];
            w1a1[tid] = acc;
        }
        __syncthreads();
        int j = (b - 32) * 256 + tid;
        float s = 0.f;
        #pragma unroll 8
        for (int c = 0; c < 32; ++c) {
            float4 v = *(const float4*)(kc_h + (size_t)j * FDIM + c * 4);
            s += v.x * w1a2_lds[c * 4 + 0] + v.y * w1a2_lds[c * 4 + 1]
               + v.z * w1a2_lds[c * 4 + 2] + v.w * w1a2_lds[c * 4 + 3];
        }
        tarr[j] = s;
        return;
    }

    // b == 36: E_sw, two k-halves, c' = ((k&63)>>3) ^ (n&7)
    #pragma unroll
    for (int u = 0; u < 8; ++u) {
        int ch = u * 256 + tid;              // 0..2047 chunks
        int half = ch >> 10;
        int rem = ch & 1023;
        int n = rem >> 3, cpp = rem & 7;
        int c = cpp ^ (n & 7);
        int kbase = half * 64 + c * 8;
        unsigned pk[4];
        #pragma unroll
        for (int i = 0; i < 4; ++i) {
            float e0 = E[(kbase + 2 * i + 0) * FDIM + n];
            float e1 = E[(kbase + 2 * i + 1) * FDIM + n];
            pk[i] = (unsigned)f2bf(e0) | ((unsigned)f2bf(e1) << 16);
        }
        *(uint4*)(E_sw + ch * 8) = make_uint4(pk[0], pk[1], pk[2], pk[3]);
    }
}

__global__ __launch_bounds__(256, 3) void gat_main(const float* __restrict__ ex_h,
                                                   const int* __restrict__ adj,
                                                   const float* __restrict__ ws,
                                                   float* __restrict__ out)
{
    const float* tarr = ws;
    const float* w1a1 = ws + N_KCC;
    const ushort_t* kc_sw = (const ushort_t*)(ws + N_KCC + FDIM);
    const ushort_t* E_sw  = kc_sw + FDIM * N_KCC;

    __shared__ __align__(16) float t_lds[N_KCC];          // 4 KB
    __shared__ __align__(16) ushort_t kc_lds[2 * 8192];   // 32 KB (E prologue / kc dbuf)
    __shared__ __align__(16) ushort_t ww_lds[4608];       // 9.2 KB (ex staging / w dbuf)
    __shared__ __align__(16) float scrA[256];
    __shared__ __align__(16) float scrB[256];
    __shared__ float w1a1_lds[FDIM];
    __shared__ float s_lds[BR], m_lds[BR], denom_lds[BR];

    const int tid  = threadIdx.x;
    const int R0   = blockIdx.x * BR;
    const int lane = tid & 63, wid = tid >> 6;
    const int l15  = lane & 15, quad = lane >> 4;

    // ---- issue E async load first (32 KB flat) ----
    #pragma unroll
    for (int u = 0; u < 8; ++u) {
        int ci = u * 256 + tid;
        async16(E_sw + ci * 8, kc_lds + ci * 8);
    }

    // ---- stage t, w1a1, ex rows ----
    #pragma unroll
    for (int u = 0; u < 4; ++u) t_lds[u * 256 + tid] = tarr[u * 256 + tid];
    if (tid < FDIM) w1a1_lds[tid] = w1a1[tid];
    const int r0 = tid >> 3;
    const int fc = (tid & 7) * 16;
    float exv[16];
    {
        const float* src = ex_h + (size_t)(R0 + r0) * FDIM + fc;
        #pragma unroll
        for (int c = 0; c < 4; ++c) {
            float4 v = *(const float4*)(src + c * 4);
            exv[c * 4 + 0] = v.x; exv[c * 4 + 1] = v.y;
            exv[c * 4 + 2] = v.z; exv[c * 4 + 3] = v.w;
        }
        unsigned pk[8];
        #pragma unroll
        for (int i = 0; i < 8; ++i)
            pk[i] = (unsigned)f2bf(exv[2 * i]) | ((unsigned)f2bf(exv[2 * i + 1]) << 16);
        *(uint4*)(ww_lds + r0 * EXS + fc)     = make_uint4(pk[0], pk[1], pk[2], pk[3]);
        *(uint4*)(ww_lds + r0 * EXS + fc + 8) = make_uint4(pk[4], pk[5], pk[6], pk[7]);
    }

    // ---- adj -> bitmasks (whole row chunk per thread, 4 groups of 8x int4) ----
    const int r_w = tid >> 3;          // adj/w row
    const int jg  = tid & 7;           // 8-j chunk within tile
    const int* abase = adj + (size_t)(R0 + r_w) * N_KCC + jg * 8;
    unsigned msk[4];
    #pragma unroll
    for (int g = 0; g < 4; ++g) {
        int4 q0 = *(const int4*)(abase + (g * 4 + 0) * 64);
        int4 q1 = *(const int4*)(abase + (g * 4 + 0) * 64 + 4);
        int4 q2 = *(const int4*)(abase + (g * 4 + 1) * 64);
        int4 q3 = *(const int4*)(abase + (g * 4 + 1) * 64 + 4);
        int4 q4 = *(const int4*)(abase + (g * 4 + 2) * 64);
        int4 q5 = *(const int4*)(abase + (g * 4 + 2) * 64 + 4);
        int4 q6 = *(const int4*)(abase + (g * 4 + 3) * 64);
        int4 q7 = *(const int4*)(abase + (g * 4 + 3) * 64 + 4);
        unsigned m = 0;
        m |= (q0.x > 0 ? 1u : 0u) << 0;  m |= (q0.y > 0 ? 1u : 0u) << 1;
        m |= (q0.z > 0 ? 1u : 0u) << 2;  m |= (q0.w > 0 ? 1u : 0u) << 3;
        m |= (q1.x > 0 ? 1u : 0u) << 4;  m |= (q1.y > 0 ? 1u : 0u) << 5;
        m |= (q1.z > 0 ? 1u : 0u) << 6;  m |= (q1.w > 0 ? 1u : 0u) << 7;
        m |= (q2.x > 0 ? 1u : 0u) << 8;  m |= (q2.y > 0 ? 1u : 0u) << 9;
        m |= (q2.z > 0 ? 1u : 0u) << 10; m |= (q2.w > 0 ? 1u : 0u) << 11;
        m |= (q3.x > 0 ? 1u : 0u) << 12; m |= (q3.y > 0 ? 1u : 0u) << 13;
        m |= (q3.z > 0 ? 1u : 0u) << 14; m |= (q3.w > 0 ? 1u : 0u) << 15;
        m |= (q4.x > 0 ? 1u : 0u) << 16; m |= (q4.y > 0 ? 1u : 0u) << 17;
        m |= (q4.z > 0 ? 1u : 0u) << 18; m |= (q4.w > 0 ? 1u : 0u) << 19;
        m |= (q5.x > 0 ? 1u : 0u) << 20; m |= (q5.y > 0 ? 1u : 0u) << 21;
        m |= (q5.z > 0 ? 1u : 0u) << 22; m |= (q5.w > 0 ? 1u : 0u) << 23;
        m |= (q6.x > 0 ? 1u : 0u) << 24; m |= (q6.y > 0 ? 1u : 0u) << 25;
        m |= (q6.z > 0 ? 1u : 0u) << 26; m |= (q6.w > 0 ? 1u : 0u) << 27;
        m |= (q7.x > 0 ? 1u : 0u) << 28; m |= (q7.y > 0 ? 1u : 0u) << 29;
        m |= (q7.z > 0 ? 1u : 0u) << 30; m |= (q7.w > 0 ? 1u : 0u) << 31;
        msk[g] = m;
    }
    __syncthreads();   // drains E async; publishes t/ex/w1a1

    // ---- Tmax + s partials ----
    {
        float mx = fmaxf(fmaxf(t_lds[tid], t_lds[256 + tid]),
                         fmaxf(t_lds[512 + tid], t_lds[768 + tid]));
        scrB[tid] = mx;
        float p = 0.f;
        #pragma unroll
        for (int i = 0; i < 16; ++i) p += exv[i] * w1a1_lds[fc + i];
        scrA[tid] = p;
    }
    __syncthreads();
    if (tid < 64)
        scrB[tid] = fmaxf(fmaxf(scrB[tid], scrB[tid + 64]),
                          fmaxf(scrB[tid + 128], scrB[tid + 192]));
    __syncthreads();
    if (tid < BR) {
        float Tm = scrB[0];
        #pragma unroll 8
        for (int i = 1; i < 64; ++i) Tm = fmaxf(Tm, scrB[i]);
        float s = 0.f;
        #pragma unroll
        for (int g = 0; g < 8; ++g) s += scrA[tid * 8 + g];
        s_lds[tid] = s;
        float x = s + Tm;
        m_lds[tid] = (x >= 0.f) ? x : LEAKY_S * x;
    }
    __syncthreads();   // publish s_lds/m_lds (R3 lesson: required)

    // ---- Eh = ex @ E via MFMA (E in kc_lds both halves, swizzled) ----
    floatx4 eh_acc[2][2], att_acc[2][2];
    #pragma unroll
    for (int mg = 0; mg < 2; ++mg)
        #pragma unroll
        for (int h = 0; h < 2; ++h) {
            eh_acc[mg][h]  = (floatx4){0.f, 0.f, 0.f, 0.f};
            att_acc[mg][h] = (floatx4){0.f, 0.f, 0.f, 0.f};
        }
    #pragma unroll
    for (int kk = 0; kk < 4; ++kk) {
        short8 a0 = *(const short8*)(ww_lds + l15 * EXS + kk * 32 + quad * 8);
        short8 a1 = *(const short8*)(ww_lds + (16 + l15) * EXS + kk * 32 + quad * 8);
        #pragma unroll
        for (int h = 0; h < 2; ++h) {
            const int n = (h * 4 + wid) * 16 + l15;
            const int cpp = ((kk & 1) * 4 + quad) ^ (n & 7);
            short8 bf = *(const short8*)(kc_lds + (kk >> 1) * 8192 + n * 64 + cpp * 8);
            eh_acc[0][h] = __builtin_amdgcn_mfma_f32_16x16x32_bf16(a0, bf, eh_acc[0][h], 0, 0, 0);
            eh_acc[1][h] = __builtin_amdgcn_mfma_f32_16x16x32_bf16(a1, bf, eh_acc[1][h], 0, 0, 0);
        }
    }
    __syncthreads();   // barrier B1: Eh LDS reads done; kc_lds/ww_lds reusable

    // ---- w generation helper state ----
    const float sr = s_lds[r_w];
    const float mr = m_lds[r_w];
    float denom_part = 0.f;

    // gen w tile jt into buffer wb
    auto genw = [&](int jt, ushort_t* wb) {
        const int jb = jt * TJ + jg * 8;
        float4 ta = *(const float4*)(t_lds + jb);
        float4 tb = *(const float4*)(t_lds + jb + 4);
        float tv[8] = {ta.x, ta.y, ta.z, ta.w, tb.x, tb.y, tb.z, tb.w};
        unsigned mb = msk[jt >> 2] >> ((jt & 3) * 8);
        float wv[8];
        #pragma unroll
        for (int e = 0; e < 8; ++e) {
            float x = sr + tv[e];
            x = fmaxf(x, LEAKY_S * x);
            float w = __expf(x - mr);
            w = ((mb >> e) & 1u) ? w : 0.f;
            denom_part += w;
            wv[e] = w;
        }
        unsigned pk[4];
        #pragma unroll
        for (int i = 0; i < 4; ++i) {
            unsigned ua = __float_as_uint(wv[2 * i + 0]) + 0x8000u;
            unsigned ub = __float_as_uint(wv[2 * i + 1]) + 0x8000u;
            pk[i] = __builtin_amdgcn_perm(ub, ua, 0x07060302);
        }
        *(uint4*)(wb + r_w * WST + jg * 8) = make_uint4(pk[0], pk[1], pk[2], pk[3]);
    };

    // ---- pipeline prologue: kc[0] async + w[0] ----
    #pragma unroll
    for (int u = 0; u < 4; ++u) {
        int ci = u * 256 + tid;
        async16(kc_sw + ci * 8, kc_lds + ci * 8);
    }
    genw(0, ww_lds);
    __syncthreads();   // barrier B2: kc[0] + w[0] ready

    // ---- main j loop: 16 tiles, one barrier each, double-buffered ----
    for (int jt = 0; jt < N_KCC / TJ; ++jt) {
        if (jt < 15) {
            const ushort_t* gsrc = kc_sw + (size_t)(jt + 1) * 8192;
            ushort_t* kdst = kc_lds + ((jt + 1) & 1) * 8192;
            #pragma unroll
            for (int u = 0; u < 4; ++u) {
                int ci = u * 256 + tid;
                async16(gsrc + ci * 8, kdst + ci * 8);
            }
            genw(jt + 1, ww_lds + ((jt + 1) & 1) * 2304);
        }
        // MFMA tile jt
        const ushort_t* kcb = kc_lds + (jt & 1) * 8192;
        const ushort_t* wb  = ww_lds + (jt & 1) * 2304;
        #pragma unroll
        for (int kk = 0; kk < 2; ++kk) {
            short8 a0 = *(const short8*)(wb + l15 * WST + kk * 32 + quad * 8);
            short8 a1 = *(const short8*)(wb + (16 + l15) * WST + kk * 32 + quad * 8);
            #pragma unroll
            for (int h = 0; h < 2; ++h) {
                const int f = (h * 4 + wid) * 16 + l15;
                const int cpp = (kk * 4 + quad) ^ (f & 7);
                short8 bf = *(const short8*)(kcb + f * 64 + cpp * 8);
                att_acc[0][h] = __builtin_amdgcn_mfma_f32_16x16x32_bf16(a0, bf, att_acc[0][h], 0, 0, 0);
                att_acc[1][h] = __builtin_amdgcn_mfma_f32_16x16x32_bf16(a1, bf, att_acc[1][h], 0, 0, 0);
            }
        }
        __syncthreads();   // next tile's kc/w ready; this tile's reads done
    }

    // ---- denominator reduce ----
    scrA[tid] = denom_part;
    __syncthreads();
    if (tid < BR) {
        float d = 0.f;
        #pragma unroll
        for (int g = 0; g < 8; ++g) d += scrA[tid * 8 + g];
        denom_lds[tid] = (d > 0.f) ? d : 1.f;
    }
    __syncthreads();

    // ---- epilogue: normalize * Eh, elu, store (C-layout: col=l15, row=quad*4+reg) ----
    #pragma unroll
    for (int mg = 0; mg < 2; ++mg) {
        float rd[4];
        #pragma unroll
        for (int reg = 0; reg < 4; ++reg)
            rd[reg] = 1.f / denom_lds[mg * 16 + quad * 4 + reg];
        #pragma unroll
        for (int h = 0; h < 2; ++h) {
            const int col = (h * 4 + wid) * 16 + l15;
            #pragma unroll
            for (int reg = 0; reg < 4; ++reg) {
                const int rl = mg * 16 + quad * 4 + reg;
                float v = att_acc[mg][h][reg] * rd[reg] * eh_acc[mg][h][reg];
                out[(size_t)(R0 + rl) * FDIM + col] = (v > 0.f) ? v : expm1f(v);
            }
        }
    }
}

extern "C" void kernel_launch(void* const* d_in, const int* in_sizes, int n_in,
                              void* d_out, int out_size, void* d_ws, size_t ws_size,
                              hipStream_t stream)
{
    const float* ex_h = (const float*)d_in[0];
    const float* kc_h = (const float*)d_in[1];
    const int*   adj  = (const int*)d_in[2];
    const float* W1   = (const float*)d_in[3];
    const float* E    = (const float*)d_in[4];
    const float* a    = (const float*)d_in[5];
    float* outp = (float*)d_out;
    float* ws   = (float*)d_ws;

    gat_prep<<<37, 256, 0, stream>>>(kc_h, W1, E, a, ws);
    gat_main<<<N_EXC / BR, 256, 0, stream>>>(ex_h, adj, ws, outp);
}